// Round 8
// baseline (352.777 us; speedup 1.0000x reference)
//
#include <hip/hip_runtime.h>
#include <math.h>

#define IMGD 224
#define HW 50176      // 224*224
#define NK 100
#define NB 8
#define OUT_PER_B 76800   // 100*16*16*3 = 300*256
#define NCHUNK 131        // chunking of 50176: 129x384 + 2x320
#define MSTR 13           // mask/ppk row stride (13 coprime 32: no bank conflicts)
#define PSLAB 640         // partials slab floats per (b,c): 600 used + pad => 2560B

// Session ledger:
// - Cross-block coherence inside a kernel: DEAD (grid.sync ~146us R3; spin/fence
//   ~1.5us/block prior session). Kernel boundary = only cheap coherence point.
// - Per-workgroup ramp: DEAD (R2). Fixed ~13us/boundary: DEAD (R4: ~0-4us).
// - Label-in-embed fusion: DEAD (+21us). Residency tail: tiny (R5: -4us).
// - Partials write false-sharing: DEAD (R7: layout fix neutral => iter's 10us
//   is latency-chain, not write-bound). R6 probe: iter body ~10us/rep, VALU 31%.
// - THIS ROUND: fold combine INTO the consuming dispatch (iter_i / label reads
//   partials_{i-1} + centers_{i-1}, redoes the 600 sequential add-chains per
//   block). Enabled by R7's chunk-major slabs: per-block read = 335KB
//   CONTIGUOUS, all-images partials (2.7MB) L2-resident per XCD => ~5us/iter
//   redundant cost vs ~10-13us/iter for the separate combine leg. Prior
//   session's "redundant recompute = 12us" verdict was an artifact of the old
//   chunk-strided layout (6288 lines/block => 210MB/iter).
//   Double-buffered partials + centers: zero intra-kernel cross-block comms.
//   22 dispatches -> 12. All FP chains verbatim => bit-exact.

static __device__ __forceinline__ float ratio_f32() {
  return (float)(10.0 / sqrt(224.0 * 224.0 / 100.0));
}

// distance op sequence — the single source of truth for bit-exactness
static __device__ __forceinline__ float dist5s(float f0, float f1, float f2,
                                               float f3, float f4, float fsq,
                                               float c0, float c1, float c2,
                                               float c3, float c4, float q) {
  float dot = __fmul_rn(f0, c0);
  dot = __fmaf_rn(f1, c1, dot);
  dot = __fmaf_rn(f2, c2, dot);
  dot = __fmaf_rn(f3, c3, dot);
  dot = __fmaf_rn(f4, c4, dot);
  return __fsub_rn(__fadd_rn(fsq, q), __fmul_rn(2.0f, dot));
}

static __device__ __forceinline__ float fsq5(float f0, float f1, float f2,
                                             float f3, float f4) {
  float s = __fmul_rn(f0, f0);
  s = __fadd_rn(s, __fmul_rn(f1, f1));
  s = __fadd_rn(s, __fmul_rn(f2, f2));
  s = __fadd_rn(s, __fmul_rn(f3, f3));
  s = __fadd_rn(s, __fmul_rn(f4, f4));
  return s;
}

// ---------- fused combine+assign: 2 chunks per 256-thread block ----------
// flag==0: self-init centers (bit-exact init chain); bx==0 persists to cout.
// flag==1: PHASE A — per-block redundant combine: 600 chains (k,comp), each
//   s = p[c=0]; for c=1..130: s = fadd(s, p[c])  (verbatim old combine order),
//   carryover from cin where cnt==0, __fdiv_rn, c2 chain; result in LDS
//   ck4/ck2; bx==0 writes centers_i to cout for dispatch i+1's carryover.
// Then the assign phase (unchanged from R5/R7-verified code) writes pout.
__global__ void __launch_bounds__(256, 4) iter_kernel(
    const float* __restrict__ x, const float* __restrict__ cin,
    float* __restrict__ cout, const float* __restrict__ pin,
    float* __restrict__ pout, int flag, float* __restrict__ Ag) {
  __shared__ float4 ck4[NK];
  __shared__ float2 ck2[NK];
  __shared__ unsigned int maskS[2][NK * MSTR];
  __shared__ unsigned short ppkS[2][NK * MSTR];
  __shared__ float4 cval4[2][384];
  __shared__ float  cvalf[2][384];
  __shared__ int cntS[2][128];
  __shared__ int offxS[2][128];
  __shared__ int wtotS[2];
  __shared__ float ubpart[2][12][10];
  __shared__ float ubg[2][12];
  __shared__ unsigned int candm[2][12][4];
  __shared__ float ared[128];
  int bx = blockIdx.x, b = blockIdx.y;
  int tid = threadIdx.x;

  if (bx >= 66) {
    // ---- A-setup block (present only in the flag==0 dispatch) ----
    for (int rr = 0; rr < 2; ++rr) {
      int p = 2 * b + rr;
      float cp = (p + 0.5f) * 14.0f - 0.5f;
      if (tid < 128) {
        // level s=128 of the old 256-wide tree: red[t] = tri(t) + tri(t+128)
        float xd0 = fabsf(cp - (float)tid) / 14.0f;
        float trip0 = fmaxf(0.0f, 1.0f - xd0);
        float trip1 = 0.0f;
        int t2 = tid + 128;
        if (t2 < IMGD) {
          float xd = fabsf(cp - (float)t2) / 14.0f;
          trip1 = fmaxf(0.0f, 1.0f - xd);
        }
        ared[tid] = trip0 + trip1;
      }
      __syncthreads();
      for (int s = 64; s > 0; s >>= 1) {
        if (tid < s) ared[tid] += ared[tid + s];
        __syncthreads();
      }
      float Zp = ared[0];
      __syncthreads();
      if (tid < IMGD) {
        float xd = fabsf(cp - (float)tid) / 14.0f;
        Ag[p * IMGD + tid] = fmaxf(0.0f, 1.0f - xd) / Zp;  // same expr as before
      }
      __syncthreads();
    }
    return;
  }

  int half = tid >> 7;
  int lt = tid & 127;
  int c = 2 * bx + half;
  int start, len;
  if (c < NCHUNK) {
    start = (c < 129) ? c * 384 : 49536 + (c - 129) * 320;
    len   = (c < 129) ? 384 : 320;
  } else {
    start = 0; len = 0;                 // bx==65 half1: inert chunk
  }

  const float ratio = ratio_f32();
  const float* x0 = x + (size_t)b * 3 * HW;
  if (flag == 0) {
    // self-init: same ops as the original setup => identical center values
    if (tid < NK) {
      int gy = tid / 10, gx = tid - 10 * (tid / 10);
      int cy = (int)((gy + 0.5) * 224.0 / 10.0);  // trunc like .astype(int32)
      int cx = (int)((gx + 0.5) * 224.0 / 10.0);
      int i = cy * IMGD + cx;
      float c0 = x0[i], c1 = x0[HW + i], c2 = x0[2 * HW + i];
      float c3 = __fmul_rn((float)cy, ratio);
      float c4 = __fmul_rn((float)cx, ratio);
      float s = __fmul_rn(c0, c0);
      s = __fadd_rn(s, __fmul_rn(c1, c1));
      s = __fadd_rn(s, __fmul_rn(c2, c2));
      s = __fadd_rn(s, __fmul_rn(c3, c3));
      s = __fadd_rn(s, __fmul_rn(c4, c4));
      ck4[tid] = make_float4(c0, c1, c2, c3);
      ck2[tid] = make_float2(c4, s);
      if (bx == 0) {   // persist centers_0 for dispatch 1's carryover
        float* oc = cout + ((size_t)b * NK + tid) * 5;
        oc[0] = c0; oc[1] = c1; oc[2] = c2; oc[3] = c3; oc[4] = c4;
      }
    }
  } else {
    // ---- PHASE A: fused redundant combine (scratch aliases cval4/cvalf,
    // phase-disjoint with the scatter that writes them later) ----
    float* sumsL  = (float*)&cval4[0][0];   // 600 floats needed, 3072 avail
    float* prevcL = &cvalf[0][0];           // 500 floats needed, 768 avail
    const float* pb = pin + (size_t)b * NCHUNK * PSLAB;
    if (tid < NK) {
      const float* cp = cin + ((size_t)b * NK + tid) * 5;
      prevcL[tid * 5 + 0] = cp[0]; prevcL[tid * 5 + 1] = cp[1];
      prevcL[tid * 5 + 2] = cp[2]; prevcL[tid * 5 + 3] = cp[3];
      prevcL[tid * 5 + 4] = cp[4];
    }
    for (int j = tid; j < NK * 6; j += 256) {
      const float* q = pb + j;
      float s = q[0];                    // C = 0 + chunk0 (exact)
      for (int cc = 1; cc < NCHUNK; ++cc)
        s = __fadd_rn(s, q[(size_t)cc * PSLAB]);
      sumsL[j] = s;
    }
    __syncthreads();
    if (tid < NK) {
      float cnt = sumsL[tid * 6 + 5];
      float v0, v1, v2, v3, v4;
      if (cnt > 0.0f) {                  // where(cnt>0, new, centers)
        float m = fmaxf(cnt, 1.0f);      // np.maximum(cnt,1.0): exact in f32
        v0 = __fdiv_rn(sumsL[tid * 6 + 0], m);
        v1 = __fdiv_rn(sumsL[tid * 6 + 1], m);
        v2 = __fdiv_rn(sumsL[tid * 6 + 2], m);
        v3 = __fdiv_rn(sumsL[tid * 6 + 3], m);
        v4 = __fdiv_rn(sumsL[tid * 6 + 4], m);
      } else {
        v0 = prevcL[tid * 5 + 0]; v1 = prevcL[tid * 5 + 1];
        v2 = prevcL[tid * 5 + 2]; v3 = prevcL[tid * 5 + 3];
        v4 = prevcL[tid * 5 + 4];
      }
      // c2 = sum(centers*centers): rounded products, sequential adds
      float t0 = __fmul_rn(v0, v0);
      t0 = __fadd_rn(t0, __fmul_rn(v1, v1));
      t0 = __fadd_rn(t0, __fmul_rn(v2, v2));
      t0 = __fadd_rn(t0, __fmul_rn(v3, v3));
      t0 = __fadd_rn(t0, __fmul_rn(v4, v4));
      ck4[tid] = make_float4(v0, v1, v2, v3);
      ck2[tid] = make_float2(v4, t0);
      if (bx == 0) {                     // persist centers_i for dispatch i+1
        float* oc = cout + ((size_t)b * NK + tid) * 5;
        oc[0] = v0; oc[1] = v1; oc[2] = v2; oc[3] = v3; oc[4] = v4;
      }
    }
    __syncthreads();
  }
  for (int t = lt; t < NK * MSTR; t += 128) maskS[half][t] = 0u;
  if (lt < 48) candm[half][lt >> 2][lt & 3] = 0u;

  // pixel loads early (no LDS dependence) — overlap with pruning phases
  float f0[3], f1[3], f2[3], f3[3], f4[3], fq[3];
  bool vld[3];
  for (int r = 0; r < 3; ++r) {
    int t = lt + r * 128;
    vld[r] = (t < len);
    int i = start + (vld[r] ? t : 0);
    int y = i / IMGD, xw = i - y * IMGD;
    f0[r] = x0[i]; f1[r] = x0[HW + i]; f2[r] = x0[2 * HW + i];
    f3[r] = __fmul_rn((float)y, ratio);
    f4[r] = __fmul_rn((float)xw, ratio);
    fq[r] = fsq5(f0[r], f1[r], f2[r], f3[r], f4[r]);
  }
  __syncthreads();

  // UB phase: thread (g,kb) scans 10 centers; group bounds in-register
  if (lt < 120) {
    int g = lt / 10, kb = lt - 10 * g;
    int i0 = start + g * 32, i1 = i0 + 31;
    int ymin = i0 / IMGD, ymax = i1 / IMGD;
    int cmin = (ymin == ymax) ? (i0 - ymin * IMGD) : 0;
    int cmax = (ymin == ymax) ? (i1 - ymax * IMGD) : (IMGD - 1);
    float f3mn = __fmul_rn((float)ymin, ratio);
    float f3mx = __fmul_rn((float)ymax, ratio);
    float f4mn = __fmul_rn((float)cmin, ratio);
    float f4mx = __fmul_rn((float)cmax, ratio);
    float mn = 3.4e38f;
    for (int k = kb * 10; k < kb * 10 + 10; ++k) {
      float c3 = ck4[k].w, c4 = ck2[k].x;
      float dy = fmaxf(fabsf(c3 - f3mn), fabsf(c3 - f3mx));
      float dx = fmaxf(fabsf(c4 - f4mn), fabsf(c4 - f4mx));
      mn = fminf(mn, dy * dy + dx * dx + 3.0f);
    }
    ubpart[half][g][kb] = mn;
  }
  __syncthreads();
  if (lt < 12) {
    float mn = ubpart[half][lt][0];
    for (int j = 1; j < 10; ++j) mn = fminf(mn, ubpart[half][lt][j]);
    ubg[half][lt] = mn + 1.0f;  // slack >> all f32 rounding at these magnitudes
  }
  __syncthreads();
  if (lt < 120) {
    int g = lt / 10, kb = lt - 10 * g;
    int i0 = start + g * 32, i1 = i0 + 31;
    int ymin = i0 / IMGD, ymax = i1 / IMGD;
    int cmin = (ymin == ymax) ? (i0 - ymin * IMGD) : 0;
    int cmax = (ymin == ymax) ? (i1 - ymax * IMGD) : (IMGD - 1);
    float f3mn = __fmul_rn((float)ymin, ratio);
    float f3mx = __fmul_rn((float)ymax, ratio);
    float f4mn = __fmul_rn((float)cmin, ratio);
    float f4mx = __fmul_rn((float)cmax, ratio);
    float lim = ubg[half][g];
    for (int k = kb * 10; k < kb * 10 + 10; ++k) {
      float c3 = ck4[k].w, c4 = ck2[k].x;
      float dy = fmaxf(0.0f, fmaxf(f3mn - c3, c3 - f3mx));
      float dx = fmaxf(0.0f, fmaxf(f4mn - c4, c4 - f4mx));
      if (dy * dy + dx * dx <= lim)
        atomicOr(&candm[half][g][k >> 5], 1u << (k & 31));
    }
  }
  __syncthreads();

  // pruned distance loop straight off the candm bitmask: k ascending
  float best[3]; int bk[3];
  for (int r = 0; r < 3; ++r) {
    best[r] = 3.4e38f; bk[r] = 0;
    int t = lt + r * 128;
    int g = (t < 384) ? (t >> 5) : 0;
    for (int w = 0; w < 4; ++w) {
      unsigned int m = candm[half][g][w];
      while (m) {
        int j = __ffs(m) - 1;
        m &= m - 1;
        int k = (w << 5) + j;
        float4 a4 = ck4[k];
        float2 a2 = ck2[k];
        float d = dist5s(f0[r], f1[r], f2[r], f3[r], f4[r], fq[r],
                         a4.x, a4.y, a4.z, a4.w, a2.x, a2.y);
        if (d < best[r]) { best[r] = d; bk[r] = k; }
      }
    }
  }
  for (int r = 0; r < 3; ++r) {
    int t = lt + r * 128;
    if (vld[r]) atomicOr(&maskS[half][bk[r] * MSTR + (t >> 5)], 1u << (t & 31));
  }
  __syncthreads();

  // per-k cumulative popcounts (stride-13 rows: conflict-free)
  int myCnt = 0;
  if (lt < NK) {
    int s = 0;
    for (int g = 0; g < 12; ++g) {
      ppkS[half][lt * MSTR + g] = (unsigned short)s;
      s += __popc(maskS[half][lt * MSTR + g]);
    }
    myCnt = s;
  }
  cntS[half][lt] = myCnt;
  __syncthreads();

  // inclusive prefix over 128 counts per half: shfl per wave + cross-wave fixup
  int v = myCnt;
  for (int d = 1; d < 64; d <<= 1) {
    int u = __shfl_up(v, d, 64);
    if ((tid & 63) >= d) v += u;
  }
  if (lt == 63) wtotS[half] = v;
  __syncthreads();
  if (lt >= 64) v += wtotS[half];
  offxS[half][lt] = v;
  __syncthreads();

  // stable VALUE scatter: pos = (off[k]-cnt[k]) + rank_within_k(t)
  for (int r = 0; r < 3; ++r) {
    int t = lt + r * 128;
    if (vld[r]) {
      int g = t >> 5, j = t & 31;
      unsigned int m = maskS[half][bk[r] * MSTR + g];
      int rank = ppkS[half][bk[r] * MSTR + g] + __popc(m & ((1u << j) - 1u));
      int pos = offxS[half][bk[r]] - cntS[half][bk[r]] + rank;
      cval4[half][pos] = make_float4(f0[r], f1[r], f2[r], f3[r]);
      cvalf[half][pos] = f4[r];
    }
  }
  __syncthreads();

  // scan: thread k walks its consecutive compacted range (ascending t)
  if (c < NCHUNK && lt < NK) {
    int n = cntS[half][lt];
    int base = offxS[half][lt] - n;
    float s0 = 0.f, s1 = 0.f, s2 = 0.f, s3 = 0.f, s4 = 0.f, s5 = 0.f;
    for (int m = 0; m < n; ++m) {
      float4 vv = cval4[half][base + m];
      float ww = cvalf[half][base + m];
      s0 = __fadd_rn(s0, vv.x);
      s1 = __fadd_rn(s1, vv.y);
      s2 = __fadd_rn(s2, vv.z);
      s3 = __fadd_rn(s3, vv.w);
      s4 = __fadd_rn(s4, ww);
      s5 += 1.0f;
    }
    // chunk-major slab [b][c][k][comp]: coalesced burst, lines block-exclusive
    float* pp = pout + ((size_t)(b * NCHUNK + c)) * PSLAB + lt * 6;
    pp[0] = s0; pp[1] = s1; pp[2] = s2; pp[3] = s3; pp[4] = s4; pp[5] = s5;
  }
}

// ---------- labels: fused combine (centers_10) + final assignment ----------
// Phase A identical to iter's; then the 2-chunk label body (validated in R3's
// fused kernel). Labels bit-identical to the full argmin (superset candidates,
// ascending-k, identical dist5s).
__global__ void __launch_bounds__(256, 4) label_kernel(
    const float* __restrict__ x, const float* __restrict__ cin,
    const float* __restrict__ pin, unsigned char* __restrict__ labels) {
  __shared__ float4 ck4[NK];
  __shared__ float2 ck2[NK];
  __shared__ float ubpart[2][12][10];
  __shared__ float ubg[2][12];
  __shared__ unsigned int candm[2][12][4];
  __shared__ float sumsL[NK * 6];
  __shared__ float prevcL[NK * 5];
  int bx = blockIdx.x, b = blockIdx.y;
  int tid = threadIdx.x;
  int half = tid >> 7;
  int lt = tid & 127;
  int c = 2 * bx + half;
  int start, len;
  if (c < NCHUNK) {
    start = (c < 129) ? c * 384 : 49536 + (c - 129) * 320;
    len   = (c < 129) ? 384 : 320;
  } else {
    start = 0; len = 0;
  }

  const float ratio = ratio_f32();
  const float* x0 = x + (size_t)b * 3 * HW;

  // ---- PHASE A: fused combine -> centers_10 in LDS ----
  {
    const float* pb = pin + (size_t)b * NCHUNK * PSLAB;
    if (tid < NK) {
      const float* cp = cin + ((size_t)b * NK + tid) * 5;
      prevcL[tid * 5 + 0] = cp[0]; prevcL[tid * 5 + 1] = cp[1];
      prevcL[tid * 5 + 2] = cp[2]; prevcL[tid * 5 + 3] = cp[3];
      prevcL[tid * 5 + 4] = cp[4];
    }
    for (int j = tid; j < NK * 6; j += 256) {
      const float* q = pb + j;
      float s = q[0];
      for (int cc = 1; cc < NCHUNK; ++cc)
        s = __fadd_rn(s, q[(size_t)cc * PSLAB]);
      sumsL[j] = s;
    }
    __syncthreads();
    if (tid < NK) {
      float cnt = sumsL[tid * 6 + 5];
      float v0, v1, v2, v3, v4;
      if (cnt > 0.0f) {
        float m = fmaxf(cnt, 1.0f);
        v0 = __fdiv_rn(sumsL[tid * 6 + 0], m);
        v1 = __fdiv_rn(sumsL[tid * 6 + 1], m);
        v2 = __fdiv_rn(sumsL[tid * 6 + 2], m);
        v3 = __fdiv_rn(sumsL[tid * 6 + 3], m);
        v4 = __fdiv_rn(sumsL[tid * 6 + 4], m);
      } else {
        v0 = prevcL[tid * 5 + 0]; v1 = prevcL[tid * 5 + 1];
        v2 = prevcL[tid * 5 + 2]; v3 = prevcL[tid * 5 + 3];
        v4 = prevcL[tid * 5 + 4];
      }
      float t0 = __fmul_rn(v0, v0);
      t0 = __fadd_rn(t0, __fmul_rn(v1, v1));
      t0 = __fadd_rn(t0, __fmul_rn(v2, v2));
      t0 = __fadd_rn(t0, __fmul_rn(v3, v3));
      t0 = __fadd_rn(t0, __fmul_rn(v4, v4));
      ck4[tid] = make_float4(v0, v1, v2, v3);
      ck2[tid] = make_float2(v4, t0);
    }
  }
  if (lt < 48) candm[half][lt >> 2][lt & 3] = 0u;

  float f0[3], f1[3], f2[3], f3[3], f4[3], fq[3];
  int ii[3];
  bool vld[3];
  for (int r = 0; r < 3; ++r) {
    int t = lt + r * 128;
    vld[r] = (t < len);
    int i = start + (vld[r] ? t : 0);
    ii[r] = i;
    int y = i / IMGD, xw = i - y * IMGD;
    f0[r] = x0[i]; f1[r] = x0[HW + i]; f2[r] = x0[2 * HW + i];
    f3[r] = __fmul_rn((float)y, ratio);
    f4[r] = __fmul_rn((float)xw, ratio);
    fq[r] = fsq5(f0[r], f1[r], f2[r], f3[r], f4[r]);
  }
  __syncthreads();

  if (lt < 120) {
    int g = lt / 10, kb = lt - 10 * g;
    int i0 = start + g * 32, i1 = i0 + 31;
    int ymin = i0 / IMGD, ymax = i1 / IMGD;
    int cmin = (ymin == ymax) ? (i0 - ymin * IMGD) : 0;
    int cmax = (ymin == ymax) ? (i1 - ymax * IMGD) : (IMGD - 1);
    float f3mn = __fmul_rn((float)ymin, ratio);
    float f3mx = __fmul_rn((float)ymax, ratio);
    float f4mn = __fmul_rn((float)cmin, ratio);
    float f4mx = __fmul_rn((float)cmax, ratio);
    float mn = 3.4e38f;
    for (int k = kb * 10; k < kb * 10 + 10; ++k) {
      float c3 = ck4[k].w, c4 = ck2[k].x;
      float dy = fmaxf(fabsf(c3 - f3mn), fabsf(c3 - f3mx));
      float dx = fmaxf(fabsf(c4 - f4mn), fabsf(c4 - f4mx));
      mn = fminf(mn, dy * dy + dx * dx + 3.0f);
    }
    ubpart[half][g][kb] = mn;
  }
  __syncthreads();
  if (lt < 12) {
    float mn = ubpart[half][lt][0];
    for (int j = 1; j < 10; ++j) mn = fminf(mn, ubpart[half][lt][j]);
    ubg[half][lt] = mn + 1.0f;
  }
  __syncthreads();
  if (lt < 120) {
    int g = lt / 10, kb = lt - 10 * g;
    int i0 = start + g * 32, i1 = i0 + 31;
    int ymin = i0 / IMGD, ymax = i1 / IMGD;
    int cmin = (ymin == ymax) ? (i0 - ymin * IMGD) : 0;
    int cmax = (ymin == ymax) ? (i1 - ymax * IMGD) : (IMGD - 1);
    float f3mn = __fmul_rn((float)ymin, ratio);
    float f3mx = __fmul_rn((float)ymax, ratio);
    float f4mn = __fmul_rn((float)cmin, ratio);
    float f4mx = __fmul_rn((float)cmax, ratio);
    float lim = ubg[half][g];
    for (int k = kb * 10; k < kb * 10 + 10; ++k) {
      float c3 = ck4[k].w, c4 = ck2[k].x;
      float dy = fmaxf(0.0f, fmaxf(f3mn - c3, c3 - f3mx));
      float dx = fmaxf(0.0f, fmaxf(f4mn - c4, c4 - f4mx));
      if (dy * dy + dx * dx <= lim)
        atomicOr(&candm[half][g][k >> 5], 1u << (k & 31));
    }
  }
  __syncthreads();

  float best[3]; int bk[3];
  for (int r = 0; r < 3; ++r) {
    best[r] = 3.4e38f; bk[r] = 0;
    int t = lt + r * 128;
    int g = (t < 384) ? (t >> 5) : 0;
    for (int w = 0; w < 4; ++w) {
      unsigned int m = candm[half][g][w];
      while (m) {
        int j = __ffs(m) - 1;
        m &= m - 1;
        int k = (w << 5) + j;
        float4 a4 = ck4[k];
        float2 a2 = ck2[k];
        float d = dist5s(f0[r], f1[r], f2[r], f3[r], f4[r], fq[r],
                         a4.x, a4.y, a4.z, a4.w, a2.x, a2.y);
        if (d < best[r]) { best[r] = d; bk[r] = k; }
      }
    }
  }
  unsigned char* lb = labels + (size_t)b * HW;
  for (int r = 0; r < 3; ++r)
    if (vld[r]) lb[ii[r]] = (unsigned char)bk[r];
}

// ---------- embed: block = (b, p, q-group-of-4); A + labels precomputed ----
__global__ void __launch_bounds__(256) embed_kernel(
    const float* __restrict__ x, const unsigned char* __restrict__ labels,
    const float* __restrict__ Ag, float* __restrict__ out) {
  __shared__ float Apv[28];
  __shared__ float Aqw[4][28];
  __shared__ float sk[4][NK * 3];
  int b = blockIdx.y;
  int p = blockIdx.x >> 2;
  int qg = blockIdx.x & 3;
  int q0 = qg * 4;
  int tid = threadIdx.x;

  int h0 = max(0, 14 * p - 7), h1 = min(IMGD - 1, 14 * p + 20);
  int hl = h1 - h0 + 1;
  int w0q[4], w1q[4];
#pragma unroll
  for (int qi = 0; qi < 4; ++qi) {
    int q = q0 + qi;
    w0q[qi] = max(0, 14 * q - 7);
    w1q[qi] = min(IMGD - 1, 14 * q + 20);
  }
  int W0 = w0q[0], W1 = w1q[3];
  int WU = W1 - W0 + 1;

  if (tid < hl) Apv[tid] = Ag[p * IMGD + h0 + tid];
  {
    int t = tid - 64;
    if (t >= 0 && t < 112) {
      int qi = t / 28, dw = t - 28 * qi;
      if (dw <= w1q[qi] - w0q[qi])
        Aqw[qi][dw] = Ag[(q0 + qi) * IMGD + w0q[qi] + dw];
    }
  }
  for (int t = tid; t < 4 * NK * 3; t += 256)
    sk[t / (NK * 3)][t % (NK * 3)] = 0.0f;
  __syncthreads();

  const float* xb = x + (size_t)b * 3 * HW;
  const unsigned char* lb = labels + (size_t)b * HW;
  int n = hl * WU;                    // <= 28*70 = 1960 <= 8*256
  for (int r = 0; r < 8; ++r) {
    int idx = tid + r * 256;
    if (idx >= n) break;
    int dh = idx / WU;
    int dcol = idx - dh * WU;
    int col = W0 + dcol;
    int i = (h0 + dh) * IMGD + col;
    float v0 = xb[i], v1 = xb[HW + i], v2 = xb[2 * HW + i];
    int k = lb[i];
    float ap = Apv[dh];
#pragma unroll
    for (int qi = 0; qi < 4; ++qi) {
      if (col >= w0q[qi] && col <= w1q[qi]) {
        float wgt = ap * Aqw[qi][col - w0q[qi]];
        atomicAdd(&sk[qi][k * 3 + 0], wgt * v0);
        atomicAdd(&sk[qi][k * 3 + 1], wgt * v1);
        atomicAdd(&sk[qi][k * 3 + 2], wgt * v2);
      }
    }
  }
  __syncthreads();

  float* outb = out + (size_t)b * OUT_PER_B;
  for (int t = tid; t < 4 * NK * 3; t += 256) {
    int qi = t / (NK * 3), t3 = t - qi * (NK * 3);
    int k = t3 / 3, cc = t3 - 3 * k;
    int base = p * 48 + (q0 + qi) * 3;
    int f = k * 768 + base + cc;              // flat [K,P,P,C] index
    outb[(f & 255) * 300 + (f >> 8)] = sk[qi][t3]; // view(B,300,256)+transpose
  }
}

extern "C" void kernel_launch(void* const* d_in, const int* in_sizes, int n_in,
                              void* d_out, int out_size, void* d_ws, size_t ws_size,
                              hipStream_t stream) {
  const float* x = (const float*)d_in[0];
  float* out = (float*)d_out;
  char* ws = (char*)d_ws;
  // ws layout (double-buffered partials + centers; boundary = coherence point):
  float* centersA       = (float*)(ws + 16384);      // 2000 B
  float* centersB       = (float*)(ws + 32768);      // 2000 B
  float* Ag             = (float*)(ws + 65536);      // 16*224*4 = 14336 B
  unsigned char* labels = (unsigned char*)(ws + 98304); // 8*50176 = 401408 B
  float* partialsA      = (float*)(ws + 1703936);    // 8*131*640*4 = 2682880 B
  float* partialsB      = (float*)(ws + 4587520);    // 2682880 B

  float* C[2] = {centersA, centersB};
  float* P[2] = {partialsA, partialsB};

  dim3 ig0(67, NB);               // bx 0..65: chunk pairs; bx 66: A-setup
  dim3 ig(66, NB);                // 528 blocks — all resident at 4 blocks/CU
  // d0: self-init assign -> C[0], P[0]
  iter_kernel<<<ig0, 256, 0, stream>>>(x, C[1], C[0], P[1], P[0], 0, Ag);
  // d1..d9: fused combine+assign, read (i-1)%2, write i%2
  for (int i = 1; i < 10; ++i)
    iter_kernel<<<ig, 256, 0, stream>>>(x, C[(i - 1) & 1], C[i & 1],
                                        P[(i - 1) & 1], P[i & 1], 1, Ag);
  // label: fused combine (centers_10 from P[1] + carryover C[1]) + assignment
  label_kernel<<<ig, 256, 0, stream>>>(x, C[1], P[1], labels);
  dim3 egrid(64, NB);             // (p*4 + qgroup) x b — 512 blocks
  embed_kernel<<<egrid, 256, 0, stream>>>(x, labels, Ag, out);
}

// Round 9
// 297.916 us; speedup vs baseline: 1.1841x; 1.1841x over previous
//
#include <hip/hip_runtime.h>
#include <math.h>

#define IMGD 224
#define HW 50176      // 224*224
#define NK 100
#define NB 8
#define OUT_PER_B 76800   // 100*16*16*3 = 300*256
#define NCHUNK 131        // chunking of 50176: 129x384 + 2x320
#define MSTR 13           // mask/ppk row stride (13 coprime 32: no bank conflicts)

// Session ledger:
// - Cross-block coherence inside a kernel: DEAD (grid.sync ~146us R3).
// - Per-workgroup ramp: DEAD (R2). Fixed ~13us/boundary: DEAD (R4: ~4-6us).
// - Label-in-embed fusion: DEAD (+21us). Residency tail: tiny (R5: -4us).
// - Partials false-sharing: DEAD (R7 neutral). Fused redundant combine: DEAD
//   TWICE (R8: +61us; phase-A ~12us/dispatch = prior session's R18 verdict —
//   528x redundant read of 2.5MB is L2-BW-bound at ~15TB/s).
// - R6 probe + R1<->R2 neutrality: iter wall = ONE block's serial phase chain
//   (~10.2us, VALUBusy 31%, ~9 barriers ~830ns/phase), occupancy-invariant.
// - THIS ROUND: revert to R5 (291.7 best) + shorten the chain: wave-ballot
//   pruning (3 phases -> 1, kills 12-thread serial reduce; fminf/ballot give
//   bit-identical candidate sets), single-wave prefix (kills wtot round-trip),
//   embed load hoist (8 serialized latency exposures -> 1).

static __device__ __forceinline__ float ratio_f32() {
  return (float)(10.0 / sqrt(224.0 * 224.0 / 100.0));
}

// distance op sequence — the single source of truth for bit-exactness
static __device__ __forceinline__ float dist5s(float f0, float f1, float f2,
                                               float f3, float f4, float fsq,
                                               float c0, float c1, float c2,
                                               float c3, float c4, float q) {
  float dot = __fmul_rn(f0, c0);
  dot = __fmaf_rn(f1, c1, dot);
  dot = __fmaf_rn(f2, c2, dot);
  dot = __fmaf_rn(f3, c3, dot);
  dot = __fmaf_rn(f4, c4, dot);
  return __fsub_rn(__fadd_rn(fsq, q), __fmul_rn(2.0f, dot));
}

static __device__ __forceinline__ float fsq5(float f0, float f1, float f2,
                                             float f3, float f4) {
  float s = __fmul_rn(f0, f0);
  s = __fadd_rn(s, __fmul_rn(f1, f1));
  s = __fadd_rn(s, __fmul_rn(f2, f2));
  s = __fadd_rn(s, __fmul_rn(f3, f3));
  s = __fadd_rn(s, __fmul_rn(f4, f4));
  return s;
}

// ---------- fused assign+partial: 2 chunks per 256-thread block ----------
// Pruning now wave-ballot: wave wv of each half handles groups wv*6..wv*6+5;
// 64 lanes evaluate centers (lane, 64+lane); shfl_xor fminf reduce (exact min,
// order-free for positive floats) -> UB; __ballot builds candm directly.
// Candidate SET identical to the old UB/candm phases (same exprs, 1.0 slack),
// walk ascending-k => argmin + first-index ties bit-preserved.
__global__ void __launch_bounds__(256, 4) iter_kernel(
    const float* __restrict__ x, float* __restrict__ centers,
    const float* __restrict__ c2g, float* __restrict__ partials, int flag,
    float* __restrict__ Ag) {
  __shared__ float4 ck4[NK];
  __shared__ float2 ck2[NK];
  __shared__ float2 ckxy[NK];
  __shared__ unsigned int maskS[2][NK * MSTR];
  __shared__ unsigned short ppkS[2][NK * MSTR];
  __shared__ float4 cval4[2][384];
  __shared__ float  cvalf[2][384];
  __shared__ int cntS[2][128];
  __shared__ int offxS[2][128];
  __shared__ unsigned int candm[2][12][4];
  __shared__ float ared[128];
  int bx = blockIdx.x, b = blockIdx.y;
  int tid = threadIdx.x;

  if (bx >= 66) {
    // ---- A-setup block (present only in the flag==0 dispatch) ----
    for (int rr = 0; rr < 2; ++rr) {
      int p = 2 * b + rr;
      float cp = (p + 0.5f) * 14.0f - 0.5f;
      if (tid < 128) {
        // level s=128 of the old 256-wide tree: red[t] = tri(t) + tri(t+128)
        float xd0 = fabsf(cp - (float)tid) / 14.0f;
        float trip0 = fmaxf(0.0f, 1.0f - xd0);
        float trip1 = 0.0f;
        int t2 = tid + 128;
        if (t2 < IMGD) {
          float xd = fabsf(cp - (float)t2) / 14.0f;
          trip1 = fmaxf(0.0f, 1.0f - xd);
        }
        ared[tid] = trip0 + trip1;
      }
      __syncthreads();
      for (int s = 64; s > 0; s >>= 1) {
        if (tid < s) ared[tid] += ared[tid + s];
        __syncthreads();
      }
      float Zp = ared[0];
      __syncthreads();
      if (tid < IMGD) {
        float xd = fabsf(cp - (float)tid) / 14.0f;
        Ag[p * IMGD + tid] = fmaxf(0.0f, 1.0f - xd) / Zp;  // same expr as before
      }
      __syncthreads();
    }
    return;
  }

  int half = tid >> 7;
  int lt = tid & 127;
  int c = 2 * bx + half;
  int start, len;
  if (c < NCHUNK) {
    start = (c < 129) ? c * 384 : 49536 + (c - 129) * 320;
    len   = (c < 129) ? 384 : 320;
  } else {
    start = 0; len = 0;                 // bx==65 half1: inert chunk
  }

  const float ratio = ratio_f32();
  const float* x0 = x + (size_t)b * 3 * HW;
  if (flag == 0) {
    // self-init: same ops as the original setup => identical center values
    if (tid < NK) {
      int gy = tid / 10, gx = tid - 10 * (tid / 10);
      int cy = (int)((gy + 0.5) * 224.0 / 10.0);  // trunc like .astype(int32)
      int cx = (int)((gx + 0.5) * 224.0 / 10.0);
      int i = cy * IMGD + cx;
      float c0 = x0[i], c1 = x0[HW + i], c2 = x0[2 * HW + i];
      float c3 = __fmul_rn((float)cy, ratio);
      float c4 = __fmul_rn((float)cx, ratio);
      float s = __fmul_rn(c0, c0);
      s = __fadd_rn(s, __fmul_rn(c1, c1));
      s = __fadd_rn(s, __fmul_rn(c2, c2));
      s = __fadd_rn(s, __fmul_rn(c3, c3));
      s = __fadd_rn(s, __fmul_rn(c4, c4));
      ck4[tid] = make_float4(c0, c1, c2, c3);
      ck2[tid] = make_float2(c4, s);
      ckxy[tid] = make_float2(c3, c4);
      if (bx == 0) {   // persist for combine#1's cnt==0 carryover
        float* oc = centers + ((size_t)b * NK + tid) * 5;
        oc[0] = c0; oc[1] = c1; oc[2] = c2; oc[3] = c3; oc[4] = c4;
      }
    }
  } else {
    const float* cb = centers + (size_t)b * NK * 5;
    const float* c2b = c2g + (size_t)b * NK;
    if (tid < NK) {
      ck4[tid] = make_float4(cb[tid*5+0], cb[tid*5+1], cb[tid*5+2], cb[tid*5+3]);
      ck2[tid] = make_float2(cb[tid*5+4], c2b[tid]);
      ckxy[tid] = make_float2(cb[tid*5+3], cb[tid*5+4]);
    }
  }
  for (int t = lt; t < NK * MSTR; t += 128) maskS[half][t] = 0u;

  // pixel loads early (no LDS dependence) — latency hides under ballot phase
  float f0[3], f1[3], f2[3], f3[3], f4[3], fq[3];
  bool vld[3];
  for (int r = 0; r < 3; ++r) {
    int t = lt + r * 128;
    vld[r] = (t < len);
    int i = start + (vld[r] ? t : 0);
    int y = i / IMGD, xw = i - y * IMGD;
    f0[r] = x0[i]; f1[r] = x0[HW + i]; f2[r] = x0[2 * HW + i];
    f3[r] = __fmul_rn((float)y, ratio);
    f4[r] = __fmul_rn((float)xw, ratio);
    fq[r] = fsq5(f0[r], f1[r], f2[r], f3[r], f4[r]);
  }
  __syncthreads();

  // wave-ballot pruning: one phase replaces UB + reduce + candm
  {
    int lane = tid & 63;
    bool has2 = (lane < 36);
    float2 cA = ckxy[lane];
    float2 cB = ckxy[has2 ? (64 + lane) : 0];
    int wv = lt >> 6;
    for (int j = 0; j < 6; ++j) {
      int g = wv * 6 + j;
      int i0 = start + g * 32, i1 = i0 + 31;
      int ymin = i0 / IMGD, ymax = i1 / IMGD;
      int cmin = (ymin == ymax) ? (i0 - ymin * IMGD) : 0;
      int cmax = (ymin == ymax) ? (i1 - ymax * IMGD) : (IMGD - 1);
      float f3mn = __fmul_rn((float)ymin, ratio);
      float f3mx = __fmul_rn((float)ymax, ratio);
      float f4mn = __fmul_rn((float)cmin, ratio);
      float f4mx = __fmul_rn((float)cmax, ratio);
      float dyA = fmaxf(fabsf(cA.x - f3mn), fabsf(cA.x - f3mx));
      float dxA = fmaxf(fabsf(cA.y - f4mn), fabsf(cA.y - f4mx));
      float mA = dyA * dyA + dxA * dxA + 3.0f;
      float dyB = fmaxf(fabsf(cB.x - f3mn), fabsf(cB.x - f3mx));
      float dxB = fmaxf(fabsf(cB.y - f4mn), fabsf(cB.y - f4mx));
      float mB = has2 ? (dyB * dyB + dxB * dxB + 3.0f) : 3.4e38f;
      float mn = fminf(mA, mB);
      for (int s = 1; s < 64; s <<= 1) mn = fminf(mn, __shfl_xor(mn, s, 64));
      float lim = mn + 1.0f;   // slack >> f32 rounding at these magnitudes
      float eyA = fmaxf(0.0f, fmaxf(f3mn - cA.x, cA.x - f3mx));
      float exA = fmaxf(0.0f, fmaxf(f4mn - cA.y, cA.y - f4mx));
      unsigned long long b1 = __ballot(eyA * eyA + exA * exA <= lim);
      float eyB = fmaxf(0.0f, fmaxf(f3mn - cB.x, cB.x - f3mx));
      float exB = fmaxf(0.0f, fmaxf(f4mn - cB.y, cB.y - f4mx));
      unsigned long long b2 = __ballot(has2 && (eyB * eyB + exB * exB <= lim));
      if (lane == 0) {
        candm[half][g][0] = (unsigned int)b1;
        candm[half][g][1] = (unsigned int)(b1 >> 32);
        candm[half][g][2] = (unsigned int)b2;
        candm[half][g][3] = (unsigned int)(b2 >> 32);
      }
    }
  }
  __syncthreads();

  // pruned distance loop straight off the candm bitmask: k ascending
  float best[3]; int bk[3];
  for (int r = 0; r < 3; ++r) {
    best[r] = 3.4e38f; bk[r] = 0;
    int t = lt + r * 128;
    int g = (t < 384) ? (t >> 5) : 0;
    for (int w = 0; w < 4; ++w) {
      unsigned int m = candm[half][g][w];
      while (m) {
        int j = __ffs(m) - 1;
        m &= m - 1;
        int k = (w << 5) + j;
        float4 a4 = ck4[k];
        float2 a2 = ck2[k];
        float d = dist5s(f0[r], f1[r], f2[r], f3[r], f4[r], fq[r],
                         a4.x, a4.y, a4.z, a4.w, a2.x, a2.y);
        if (d < best[r]) { best[r] = d; bk[r] = k; }
      }
    }
  }
  for (int r = 0; r < 3; ++r) {
    int t = lt + r * 128;
    if (vld[r]) atomicOr(&maskS[half][bk[r] * MSTR + (t >> 5)], 1u << (t & 31));
  }
  __syncthreads();

  // per-k cumulative popcounts (stride-13 rows: conflict-free)
  int myCnt = 0;
  if (lt < NK) {
    int s = 0;
    for (int g = 0; g < 12; ++g) {
      ppkS[half][lt * MSTR + g] = (unsigned short)s;
      s += __popc(maskS[half][lt * MSTR + g]);
    }
    myCnt = s;
  }
  cntS[half][lt] = myCnt;
  __syncthreads();

  // inclusive prefix over 128 counts: wave0 of each half, 2 counts/lane
  if ((lt >> 6) == 0) {
    int a0 = cntS[half][2 * lt];
    int a1 = cntS[half][2 * lt + 1];
    int v = a0 + a1;
    for (int d = 1; d < 64; d <<= 1) {
      int u = __shfl_up(v, d, 64);
      if (lt >= d) v += u;
    }
    offxS[half][2 * lt + 1] = v;
    offxS[half][2 * lt]     = v - a1;
  }
  __syncthreads();

  // stable VALUE scatter: pos = (off[k]-cnt[k]) + rank_within_k(t)
  for (int r = 0; r < 3; ++r) {
    int t = lt + r * 128;
    if (vld[r]) {
      int g = t >> 5, j = t & 31;
      unsigned int m = maskS[half][bk[r] * MSTR + g];
      int rank = ppkS[half][bk[r] * MSTR + g] + __popc(m & ((1u << j) - 1u));
      int pos = offxS[half][bk[r]] - cntS[half][bk[r]] + rank;
      cval4[half][pos] = make_float4(f0[r], f1[r], f2[r], f3[r]);
      cvalf[half][pos] = f4[r];
    }
  }
  __syncthreads();

  // scan: thread k walks its consecutive compacted range (ascending t)
  if (c < NCHUNK && lt < NK) {
    int n = cntS[half][lt];
    int base = offxS[half][lt] - n;
    float s0 = 0.f, s1 = 0.f, s2 = 0.f, s3 = 0.f, s4 = 0.f, s5 = 0.f;
    for (int m = 0; m < n; ++m) {
      float4 vv = cval4[half][base + m];
      float ww = cvalf[half][base + m];
      s0 = __fadd_rn(s0, vv.x);
      s1 = __fadd_rn(s1, vv.y);
      s2 = __fadd_rn(s2, vv.z);
      s3 = __fadd_rn(s3, vv.w);
      s4 = __fadd_rn(s4, ww);
      s5 += 1.0f;
    }
    // k-major layout [b][k][j][c]: combine reads contiguous
    float* pp = partials + ((size_t)(b * NK + lt) * 6) * NCHUNK + c;
    pp[0 * NCHUNK] = s0; pp[1 * NCHUNK] = s1; pp[2 * NCHUNK] = s2;
    pp[3 * NCHUNK] = s3; pp[4 * NCHUNK] = s4; pp[5 * NCHUNK] = s5;
  }
}

// ---------- combine: 8 bk-rows per block; LDS-staged 131-chains ----------
// Per-row op order identical to the original 1-row/block version (sequential
// adds chunk0..130; c2 chain sequential) => centers/c2 bit-identical.
__global__ void __launch_bounds__(256) combine_update_kernel(
    float* __restrict__ centers, const float* __restrict__ partials,
    float* __restrict__ c2g) {
  __shared__ float st[8 * 6 * NCHUNK];
  __shared__ float sums[8][6];
  __shared__ float newc[8][5];
  int bb = blockIdx.x;                 // handles bk in [bb*8, bb*8+8)
  int tid = threadIdx.x;
  const float* base = partials + (size_t)bb * 8 * 6 * NCHUNK;
  // 6288 floats = 1572 float4 (both pointers 16B-aligned)
  for (int t = tid; t < (8 * 6 * NCHUNK) / 4; t += 256)
    ((float4*)st)[t] = ((const float4*)base)[t];
  __syncthreads();
  if (tid < 48) {
    int row = tid / 6, comp = tid - 6 * (tid / 6);
    const float* rp = st + (row * 6 + comp) * NCHUNK;
    float s = rp[0];                   // C = 0 + chunk0 (exact)
    for (int c = 1; c < NCHUNK; ++c) s = __fadd_rn(s, rp[c]);
    sums[row][comp] = s;
  }
  __syncthreads();
  if (tid < 40) {
    int row = tid / 5, d = tid - 5 * (tid / 5);
    float cntv = sums[row][5];
    float* cc = centers + (size_t)(bb * 8 + row) * 5;
    float v;
    if (cntv > 0.0f) {                 // where(cnt>0, new, centers)
      float m = fmaxf(cntv, 1.0f);     // np.maximum(cnt,1.0): exact int in f32
      v = __fdiv_rn(sums[row][d], m);
      cc[d] = v;
    } else {
      v = cc[d];                       // unchanged center
    }
    newc[row][d] = v;
  }
  __syncthreads();
  if (tid < 8) {
    // c2 = sum(centers*centers): rounded products, sequential adds
    float t0 = __fmul_rn(newc[tid][0], newc[tid][0]);
    t0 = __fadd_rn(t0, __fmul_rn(newc[tid][1], newc[tid][1]));
    t0 = __fadd_rn(t0, __fmul_rn(newc[tid][2], newc[tid][2]));
    t0 = __fadd_rn(t0, __fmul_rn(newc[tid][3], newc[tid][3]));
    t0 = __fadd_rn(t0, __fmul_rn(newc[tid][4], newc[tid][4]));
    c2g[bb * 8 + tid] = t0;
  }
}

// ---------- labels: final assignment w.r.t. centers_10, written ONCE --------
// Same wave-ballot pruning; candidates ascending-k => labels bit-identical.
__global__ void __launch_bounds__(128, 4) label_kernel(
    const float* __restrict__ x, const float* __restrict__ centers,
    const float* __restrict__ c2g, unsigned char* __restrict__ labels) {
  __shared__ float4 ck4[NK];
  __shared__ float2 ck2[NK];
  __shared__ float2 ckxy[NK];
  __shared__ unsigned int candm[12][4];
  int c = blockIdx.x, b = blockIdx.y;
  int tid = threadIdx.x;
  int start = (c < 129) ? c * 384 : 49536 + (c - 129) * 320;
  int len   = (c < 129) ? 384 : 320;

  const float ratio = ratio_f32();
  const float* x0 = x + (size_t)b * 3 * HW;
  const float* cb = centers + (size_t)b * NK * 5;
  const float* c2b = c2g + (size_t)b * NK;
  if (tid < NK) {
    ck4[tid] = make_float4(cb[tid*5+0], cb[tid*5+1], cb[tid*5+2], cb[tid*5+3]);
    ck2[tid] = make_float2(cb[tid*5+4], c2b[tid]);
    ckxy[tid] = make_float2(cb[tid*5+3], cb[tid*5+4]);
  }

  float f0[3], f1[3], f2[3], f3[3], f4[3], fq[3];
  int ii[3];
  bool vld[3];
  for (int r = 0; r < 3; ++r) {
    int t = tid + r * 128;
    vld[r] = (t < len);
    int i = start + (vld[r] ? t : 0);
    ii[r] = i;
    int y = i / IMGD, xw = i - y * IMGD;
    f0[r] = x0[i]; f1[r] = x0[HW + i]; f2[r] = x0[2 * HW + i];
    f3[r] = __fmul_rn((float)y, ratio);
    f4[r] = __fmul_rn((float)xw, ratio);
    fq[r] = fsq5(f0[r], f1[r], f2[r], f3[r], f4[r]);
  }
  __syncthreads();

  {
    int lane = tid & 63;
    bool has2 = (lane < 36);
    float2 cA = ckxy[lane];
    float2 cB = ckxy[has2 ? (64 + lane) : 0];
    int wv = tid >> 6;
    for (int j = 0; j < 6; ++j) {
      int g = wv * 6 + j;
      int i0 = start + g * 32, i1 = i0 + 31;
      int ymin = i0 / IMGD, ymax = i1 / IMGD;
      int cmin = (ymin == ymax) ? (i0 - ymin * IMGD) : 0;
      int cmax = (ymin == ymax) ? (i1 - ymax * IMGD) : (IMGD - 1);
      float f3mn = __fmul_rn((float)ymin, ratio);
      float f3mx = __fmul_rn((float)ymax, ratio);
      float f4mn = __fmul_rn((float)cmin, ratio);
      float f4mx = __fmul_rn((float)cmax, ratio);
      float dyA = fmaxf(fabsf(cA.x - f3mn), fabsf(cA.x - f3mx));
      float dxA = fmaxf(fabsf(cA.y - f4mn), fabsf(cA.y - f4mx));
      float mA = dyA * dyA + dxA * dxA + 3.0f;
      float dyB = fmaxf(fabsf(cB.x - f3mn), fabsf(cB.x - f3mx));
      float dxB = fmaxf(fabsf(cB.y - f4mn), fabsf(cB.y - f4mx));
      float mB = has2 ? (dyB * dyB + dxB * dxB + 3.0f) : 3.4e38f;
      float mn = fminf(mA, mB);
      for (int s = 1; s < 64; s <<= 1) mn = fminf(mn, __shfl_xor(mn, s, 64));
      float lim = mn + 1.0f;
      float eyA = fmaxf(0.0f, fmaxf(f3mn - cA.x, cA.x - f3mx));
      float exA = fmaxf(0.0f, fmaxf(f4mn - cA.y, cA.y - f4mx));
      unsigned long long b1 = __ballot(eyA * eyA + exA * exA <= lim);
      float eyB = fmaxf(0.0f, fmaxf(f3mn - cB.x, cB.x - f3mx));
      float exB = fmaxf(0.0f, fmaxf(f4mn - cB.y, cB.y - f4mx));
      unsigned long long b2 = __ballot(has2 && (eyB * eyB + exB * exB <= lim));
      if (lane == 0) {
        candm[g][0] = (unsigned int)b1;
        candm[g][1] = (unsigned int)(b1 >> 32);
        candm[g][2] = (unsigned int)b2;
        candm[g][3] = (unsigned int)(b2 >> 32);
      }
    }
  }
  __syncthreads();

  float best[3]; int bk[3];
  for (int r = 0; r < 3; ++r) {
    best[r] = 3.4e38f; bk[r] = 0;
    int t = tid + r * 128;
    int g = (t < 384) ? (t >> 5) : 0;
    for (int w = 0; w < 4; ++w) {
      unsigned int m = candm[g][w];
      while (m) {
        int j = __ffs(m) - 1;
        m &= m - 1;
        int k = (w << 5) + j;
        float4 a4 = ck4[k];
        float2 a2 = ck2[k];
        float d = dist5s(f0[r], f1[r], f2[r], f3[r], f4[r], fq[r],
                         a4.x, a4.y, a4.z, a4.w, a2.x, a2.y);
        if (d < best[r]) { best[r] = d; bk[r] = k; }
      }
    }
  }
  unsigned char* lb = labels + (size_t)b * HW;
  for (int r = 0; r < 3; ++r)
    if (vld[r]) lb[ii[r]] = (unsigned char)bk[r];
}

// ---------- embed: block = (b, p, q-group-of-4); A + labels precomputed ----
// All 8 r-iterations' global loads hoisted (predicated, no break): one
// latency exposure instead of 8 serialized ones.
__global__ void __launch_bounds__(256) embed_kernel(
    const float* __restrict__ x, const unsigned char* __restrict__ labels,
    const float* __restrict__ Ag, float* __restrict__ out) {
  __shared__ float Apv[28];
  __shared__ float Aqw[4][28];
  __shared__ float sk[4][NK * 3];
  int b = blockIdx.y;
  int p = blockIdx.x >> 2;
  int qg = blockIdx.x & 3;
  int q0 = qg * 4;
  int tid = threadIdx.x;

  int h0 = max(0, 14 * p - 7), h1 = min(IMGD - 1, 14 * p + 20);
  int hl = h1 - h0 + 1;
  int w0q[4], w1q[4];
#pragma unroll
  for (int qi = 0; qi < 4; ++qi) {
    int q = q0 + qi;
    w0q[qi] = max(0, 14 * q - 7);
    w1q[qi] = min(IMGD - 1, 14 * q + 20);
  }
  int W0 = w0q[0], W1 = w1q[3];
  int WU = W1 - W0 + 1;

  if (tid < hl) Apv[tid] = Ag[p * IMGD + h0 + tid];
  {
    int t = tid - 64;
    if (t >= 0 && t < 112) {
      int qi = t / 28, dw = t - 28 * qi;
      if (dw <= w1q[qi] - w0q[qi])
        Aqw[qi][dw] = Ag[(q0 + qi) * IMGD + w0q[qi] + dw];
    }
  }
  for (int t = tid; t < 4 * NK * 3; t += 256)
    sk[t / (NK * 3)][t % (NK * 3)] = 0.0f;

  const float* xb = x + (size_t)b * 3 * HW;
  const unsigned char* lb = labels + (size_t)b * HW;
  int n = hl * WU;                    // <= 28*70 = 1960 <= 8*256
  float pv0[8], pv1[8], pv2[8];
  int pk[8], pdh[8], pdc[8];
#pragma unroll
  for (int r = 0; r < 8; ++r) {
    int idx = tid + r * 256;
    int idc = (idx < n) ? idx : 0;
    int dh = idc / WU;
    int dcol = idc - dh * WU;
    int i = (h0 + dh) * IMGD + (W0 + dcol);
    pv0[r] = xb[i]; pv1[r] = xb[HW + i]; pv2[r] = xb[2 * HW + i];
    pk[r] = lb[i];
    pdh[r] = dh; pdc[r] = dcol;
  }
  __syncthreads();

#pragma unroll
  for (int r = 0; r < 8; ++r) {
    int idx = tid + r * 256;
    if (idx < n) {
      int col = W0 + pdc[r];
      float ap = Apv[pdh[r]];
      int k = pk[r];
#pragma unroll
      for (int qi = 0; qi < 4; ++qi) {
        if (col >= w0q[qi] && col <= w1q[qi]) {
          float wgt = ap * Aqw[qi][col - w0q[qi]];
          atomicAdd(&sk[qi][k * 3 + 0], wgt * pv0[r]);
          atomicAdd(&sk[qi][k * 3 + 1], wgt * pv1[r]);
          atomicAdd(&sk[qi][k * 3 + 2], wgt * pv2[r]);
        }
      }
    }
  }
  __syncthreads();

  float* outb = out + (size_t)b * OUT_PER_B;
  for (int t = tid; t < 4 * NK * 3; t += 256) {
    int qi = t / (NK * 3), t3 = t - qi * (NK * 3);
    int k = t3 / 3, cc = t3 - 3 * k;
    int base = p * 48 + (q0 + qi) * 3;
    int f = k * 768 + base + cc;              // flat [K,P,P,C] index
    outb[(f & 255) * 300 + (f >> 8)] = sk[qi][t3]; // view(B,300,256)+transpose
  }
}

extern "C" void kernel_launch(void* const* d_in, const int* in_sizes, int n_in,
                              void* d_out, int out_size, void* d_ws, size_t ws_size,
                              hipStream_t stream) {
  const float* x = (const float*)d_in[0];
  float* out = (float*)d_out;
  char* ws = (char*)d_ws;
  // ws layout:
  float* centers        = (float*)(ws + 16384);      // 16000 B
  float* c2g            = (float*)(ws + 49152);      // 3200 B
  float* Ag             = (float*)(ws + 65536);      // 16*224*4 = 14336 B
  unsigned char* labels = (unsigned char*)(ws + 98304); // 8*50176 = 401408 B
  float* partials       = (float*)(ws + 1703936);    // 8*100*6*131*4 = 2515200 B

  dim3 ig0(67, NB);               // bx 0..65: chunk pairs; bx 66: A-setup
  dim3 ig(66, NB);                // 528 blocks — all resident at 4 blocks/CU
  iter_kernel<<<ig0, 256, 0, stream>>>(x, centers, c2g, partials, 0, Ag);
  combine_update_kernel<<<NB * NK / 8, 256, 0, stream>>>(centers, partials, c2g);
  for (int it = 1; it < 10; ++it) {
    iter_kernel<<<ig, 256, 0, stream>>>(x, centers, c2g, partials, 1, Ag);
    combine_update_kernel<<<NB * NK / 8, 256, 0, stream>>>(centers, partials, c2g);
  }
  label_kernel<<<dim3(NCHUNK, NB), 128, 0, stream>>>(x, centers, c2g, labels);
  dim3 egrid(64, NB);             // (p*4 + qgroup) x b — 512 blocks
  embed_kernel<<<egrid, 256, 0, stream>>>(x, labels, Ag, out);
}